// Round 1
// baseline (77.066 us; speedup 1.0000x reference)
//
#include <hip/hip_runtime.h>
#include <hip/hip_fp16.h>

static constexpr int W56 = 56;
static constexpr int SP  = 56 * 56;   // 3136 = 49*64
static constexpr int CHN = 64;

// ---------------------------------------------------------------------------
// Prep kernel (one-shot, tiny): fp32 LUT (16cb x 16e x 64ch = 64KB) -> fp16
// (32KB) in d_ws, pre-swizzled per 16B chunk.
// Logical layout: 256 rows (row = cb*16+e) x 64 half (128B = 8 chunks x 16B).
// Linear slot r*8+c stores logical chunk (c ^ (r&7)) of row r.  This lets the
// main kernel copy ws -> LDS with plain linear global_load_lds (wave-uniform
// base + lane*16), while phase-2 reads chunk (2q+i)^(row&7): rows start at
// bank 0 but the XOR rotates per-row so only e vs e+8 alias (free 2-way).
// ---------------------------------------------------------------------------
__global__ __launch_bounds__(256) void lut_prep(const float* __restrict__ lut,
                                                __half* __restrict__ wlut) {
    const int t = blockIdx.x * 256 + threadIdx.x;   // 0..2047 (one 16B chunk each)
    const int r = t >> 3;
    const int c = (t & 7) ^ (r & 7);                // logical chunk for this slot
    const float4* src = reinterpret_cast<const float4*>(lut + r * 64 + c * 8);
    const float4 f0 = src[0];
    const float4 f1 = src[1];
    __half2 h[4];
    h[0] = __float22half2_rn(make_float2(f0.x, f0.y));
    h[1] = __float22half2_rn(make_float2(f0.z, f0.w));
    h[2] = __float22half2_rn(make_float2(f1.x, f1.y));
    h[3] = __float22half2_rn(make_float2(f1.z, f1.w));
    *reinterpret_cast<float4*>(wlut + t * 8) = *reinterpret_cast<const float4*>(h);
}

// async global -> LDS, 16B per lane (dest = uniform base + lane*16)
__device__ __forceinline__ void async_copy16(const void* g, void* l) {
    __builtin_amdgcn_global_load_lds(
        (const __attribute__((address_space(1))) void*)g,
        (__attribute__((address_space(3))) void*)l,
        16, 0, 0);
}

// ---------------------------------------------------------------------------
// Fused kernel. grid = 784 blocks (16 b * 49 point-groups), block = 256.
// Block covers 64 consecutive points x all 64 channels.
// Phase 1: wave 'pu' encodes codebooks [4pu,4pu+4) for the 64 points.
//          All si/sv index math is wave-uniform (readfirstlane'd pu) -> SALU +
//          s_load; x gathers issued first (longest latency, cold HBM after the
//          harness poison-fill evicts L3).  LUT staging is 8 async
//          global_load_lds of the pre-converted fp16 ws (32KB/block total).
// Phase 2: wave 'pu' = channel quarter q; sums 16 fp16 LUT rows + fp32 bias.
// LDS: 32KB LUT + 512B codes = 33.3KB -> 4 blocks/CU (was 3 with fp32 pad).
// ---------------------------------------------------------------------------
__global__ __launch_bounds__(256, 4) void maddness_fused(
    const float*  __restrict__ x,
    const int*    __restrict__ si,
    const float*  __restrict__ sv,
    const __half* __restrict__ wlut,
    const float*  __restrict__ bias,
    float*        __restrict__ out)
{
    __shared__ __half2        lutLds[256 * 32];   // packed, chunk-swizzled
    __shared__ unsigned short codes[256];

    const int tid  = threadIdx.x;
    const int part = tid >> 6;
    const int lane = tid & 63;
    const int pu   = __builtin_amdgcn_readfirstlane(part);  // SGPR wave id

    const int p  = blockIdx.x * 64 + lane;        // < 50176 exactly
    const int b  = p / SP;
    const int s  = p - b * SP;
    const int y  = s / W56;
    const int xc = s - y * W56;
    const float* __restrict__ xb = x + b * (CHN * SP);

    // ---- x gathers FIRST (branch-free, coalesced 256B/wave, HBM-cold) ----
    const int* __restrict__ sip = si + pu * 16;   // uniform -> s_load
    float v[4][4];
    #pragma unroll
    for (int c = 0; c < 4; ++c) {
        #pragma unroll
        for (int t = 0; t < 4; ++t) {
            const int cb = pu * 4 + c;
            const int g  = sip[c * 4 + t] + cb * 36;   // SALU (magic-div by 9/3)
            const int ch = g / 9;
            const int k9 = g - ch * 9;
            const int ki = k9 / 3;
            const int dy = ki - 1;
            const int dx = (k9 - ki * 3) - 1;
            const int yy = y + dy, xx = xc + dx;
            const bool ok = ((unsigned)yy < (unsigned)W56) & ((unsigned)xx < (unsigned)W56);
            const int yyc = min(max(yy, 0), W56 - 1);
            const int xxc = min(max(xx, 0), W56 - 1);
            const float lv = xb[ch * SP + yyc * W56 + xxc];
            v[c][t] = ok ? lv : 0.0f;
        }
    }

    // ---- async LUT staging: wave pu copies its 8KB quarter, 8 x 1KB ----
    {
        const char* gsrc = reinterpret_cast<const char*>(wlut) + pu * 8192 + lane * 16;
        char*       ldst = reinterpret_cast<char*>(lutLds) + pu * 8192;
        #pragma unroll
        for (int i = 0; i < 8; ++i)
            async_copy16(gsrc + i * 1024, ldst + i * 1024);
    }

    // ---- breadth-first thresholds: wave-uniform -> s_load into SGPRs ----
    const float* __restrict__ svp = sv + pu * 128;
    float T0[4], T1[4][2], T2[4][4], T3[4][8];
    #pragma unroll
    for (int c = 0; c < 4; ++c) {
        const int base = c * 32;
        T0[c] = svp[base];
        #pragma unroll
        for (int j = 0; j < 2; ++j) T1[c][j] = svp[base + 8  + j];
        #pragma unroll
        for (int j = 0; j < 4; ++j) T2[c][j] = svp[base + 16 + j];
        #pragma unroll
        for (int j = 0; j < 8; ++j) T3[c][j] = svp[base + 24 + j];
    }

    // ---- pure-VALU select-tree encode ----
    unsigned code = 0;
    #pragma unroll
    for (int c = 0; c < 4; ++c) {
        const bool b0 = v[c][0] >= T0[c];
        const float t1 = b0 ? T1[c][1] : T1[c][0];
        const bool b1 = v[c][1] >= t1;
        const float s01 = b1 ? T2[c][1] : T2[c][0];
        const float s23 = b1 ? T2[c][3] : T2[c][2];
        const bool b2 = v[c][2] >= (b0 ? s23 : s01);
        const float w0 = b2 ? T3[c][1] : T3[c][0];
        const float w1 = b2 ? T3[c][3] : T3[c][2];
        const float w2 = b2 ? T3[c][5] : T3[c][4];
        const float w3 = b2 ? T3[c][7] : T3[c][6];
        const float z0 = b1 ? w1 : w0;
        const float z1 = b1 ? w3 : w2;
        const bool b3 = v[c][3] >= (b0 ? z1 : z0);
        const int e = ((int)b0 << 3) | ((int)b1 << 2) | ((int)b2 << 1) | (int)b3;
        code |= (unsigned)e << (4 * c);
    }
    codes[part * 64 + lane] = (unsigned short)code;
    __syncthreads();   // drains vmcnt(0): staged LDS + codes both ready

    // ---- phase 2: decode. wave 'pu' = channel quarter q ----
    const int q = part;
    const unsigned cd0 = codes[lane];
    const unsigned cd1 = codes[64 + lane];
    const unsigned cd2 = codes[128 + lane];
    const unsigned cd3 = codes[192 + lane];

    __half2 acc[8];
    #pragma unroll
    for (int r = 0; r < 8; ++r) acc[r] = __half2{__half(0.0f), __half(0.0f)};

    #pragma unroll
    for (int cb = 0; cb < 16; ++cb) {
        const unsigned cw = (cb < 4) ? cd0 : (cb < 8) ? cd1 : (cb < 12) ? cd2 : cd3;
        const int e   = (int)((cw >> ((cb & 3) * 4)) & 15u);
        const int row = cb * 16 + e;
        const int swz = e & 7;                       // row & 7 == e & 7
        const int c0  = (2 * q) ^ swz;               // chunk holding halves [16q,16q+8)
        const int c1  = c0 ^ 1;                      // chunk holding halves [16q+8,16q+16)
        const __half2* __restrict__ base = &lutLds[row * 32];
        const float4 ra = *reinterpret_cast<const float4*>(base + c0 * 4);
        const float4 rb = *reinterpret_cast<const float4*>(base + c1 * 4);
        const __half2* ha = reinterpret_cast<const __half2*>(&ra);
        const __half2* hb = reinterpret_cast<const __half2*>(&rb);
        #pragma unroll
        for (int r = 0; r < 4; ++r) {
            acc[r]     += ha[r];
            acc[4 + r] += hb[r];
        }
    }

    float* __restrict__ op = out + b * (CHN * SP) + (q * 16) * SP + s;
    const float* __restrict__ bq = bias + q * 16;
    #pragma unroll
    for (int r = 0; r < 8; ++r) {
        const float2 f = __half22float2(acc[r]);
        op[(2 * r)     * SP] = f.x + bq[2 * r];
        op[(2 * r + 1) * SP] = f.y + bq[2 * r + 1];
    }
}

extern "C" void kernel_launch(void* const* d_in, const int* in_sizes, int n_in,
                              void* d_out, int out_size, void* d_ws, size_t ws_size,
                              hipStream_t stream) {
    const float* x  = (const float*)d_in[0];
    const int*   si = (const int*)  d_in[1];
    const float* sv = (const float*)d_in[2];
    const float* lt = (const float*)d_in[3];
    const float* bs = (const float*)d_in[4];
    float* o = (float*)d_out;
    __half* wlut = (__half*)d_ws;   // 32KB of workspace

    lut_prep<<<dim3(8), dim3(256), 0, stream>>>(lt, wlut);
    maddness_fused<<<dim3(784), dim3(256), 0, stream>>>(x, si, sv, wlut, bs, o);
}